// Round 1
// baseline (14539.325 us; speedup 1.0000x reference)
//
#include <hip/hip_runtime.h>
#include <math.h>

// LTC liquid-cell scan. B=128 independent sequential chains, one persistent
// workgroup each. x[512] lives in LDS across all T*K=1536 unfolds.
// W_rec/W_in are transposed once per launch into d_ws so the GEMV streams
// coalesced float4 rows of W^T with x broadcast from LDS.
// Roofline: per-CU L2 path bound, ~1536 MB W_rec^T per CU @ ~150 GB/s -> ~10-12 ms.

#define NN 512
#define FF 256
#define KK 6
#define BB 128
#define TT 256

__global__ void transpose_k(const float* __restrict__ W, float* __restrict__ WT,
                            int rows, int cols) {
  // W is [rows][cols], WT is [cols][rows]
  __shared__ float tile[32][33];
  const int c0 = blockIdx.x * 32;
  const int r0 = blockIdx.y * 32;
  for (int j = threadIdx.y; j < 32; j += 8)
    tile[j][threadIdx.x] = W[(size_t)(r0 + j) * cols + (c0 + threadIdx.x)];
  __syncthreads();
  for (int j = threadIdx.y; j < 32; j += 8)
    WT[(size_t)(c0 + j) * rows + (r0 + threadIdx.x)] = tile[threadIdx.x][j];
}

__global__ __launch_bounds__(1024) void liquid_kernel(
    const float* __restrict__ I,     // [B][T][F]
    const float* __restrict__ DT,    // [B][T]
    const float* __restrict__ WrT,   // [N][N]  WrT[k][n] = W_rec[n][k]
    const float* __restrict__ WiT,   // [F][N]  WiT[f][n] = W_in[n][f]
    const float* __restrict__ bv,    // [N]
    const float* __restrict__ Av,    // [N]
    const float* __restrict__ tauv,  // [N]
    float* __restrict__ out)         // [B][T][N]
{
  __shared__ float xs[NN];           // recurrent state
  __shared__ float irow[FF];         // current input row
  __shared__ float partial[8][NN];   // 8 k-group partial sums (16 KB)

  const int b   = blockIdx.x;
  const int tid = threadIdx.x;
  const int g   = tid >> 7;          // k-group 0..7
  const int c   = tid & 127;         // owns neurons 4c..4c+3 within group

  float rA = 0.f, rInvTau = 0.f, rB = 0.f;
  if (tid < NN) {
    rA      = Av[tid];
    rInvTau = 1.0f / tauv[tid];
    rB      = bv[tid];
    xs[tid] = 0.0f;                  // x0 = tanh(0) = 0
  }

  const float* Ib  = I  + (size_t)b * TT * FF;
  const float* dtb = DT + (size_t)b * TT;
  float*      outb = out + (size_t)b * TT * NN;

  __syncthreads();

  for (int t = 0; t < TT; ++t) {
    if (tid < FF) irow[tid] = Ib[(size_t)t * FF + tid];
    __syncthreads();

    // ---- inp = i_t @ W_in^T + b : 8 k-groups of 32 ----
    {
      float ax = 0.f, ay = 0.f, az = 0.f, aw = 0.f;
      const float*  wp = WiT + (size_t)(g * 32) * NN + 4 * c;
      const float4* xp = (const float4*)(irow + g * 32);
      #pragma unroll
      for (int j = 0; j < 8; ++j) {
        float4 xv = xp[j];
        float4 w0 = *(const float4*)(wp + (size_t)(4 * j + 0) * NN);
        float4 w1 = *(const float4*)(wp + (size_t)(4 * j + 1) * NN);
        float4 w2 = *(const float4*)(wp + (size_t)(4 * j + 2) * NN);
        float4 w3 = *(const float4*)(wp + (size_t)(4 * j + 3) * NN);
        ax += w0.x * xv.x + w1.x * xv.y + w2.x * xv.z + w3.x * xv.w;
        ay += w0.y * xv.x + w1.y * xv.y + w2.y * xv.z + w3.y * xv.w;
        az += w0.z * xv.x + w1.z * xv.y + w2.z * xv.z + w3.z * xv.w;
        aw += w0.w * xv.x + w1.w * xv.y + w2.w * xv.z + w3.w * xv.w;
      }
      *(float4*)&partial[g][4 * c] = make_float4(ax, ay, az, aw);
    }
    __syncthreads();

    float rInp = 0.f;
    if (tid < NN) {
      float s = rB;
      #pragma unroll
      for (int gg = 0; gg < 8; ++gg) s += partial[gg][tid];
      rInp = s;
    }
    const float dtk = dtb[t] * (1.0f / KK);
    __syncthreads();   // all partial reads done before unfold 0 overwrites

    // ---- K semi-implicit unfolds ----
    float xcur = 0.f;
    #pragma unroll 1
    for (int kk = 0; kk < KK; ++kk) {
      float ax = 0.f, ay = 0.f, az = 0.f, aw = 0.f;
      const float*  wp = WrT + (size_t)(g * 64) * NN + 4 * c;
      const float4* xp = (const float4*)(xs + g * 64);
      #pragma unroll 4
      for (int j = 0; j < 16; ++j) {
        float4 xv = xp[j];
        float4 w0 = *(const float4*)(wp + (size_t)(4 * j + 0) * NN);
        float4 w1 = *(const float4*)(wp + (size_t)(4 * j + 1) * NN);
        float4 w2 = *(const float4*)(wp + (size_t)(4 * j + 2) * NN);
        float4 w3 = *(const float4*)(wp + (size_t)(4 * j + 3) * NN);
        ax += w0.x * xv.x + w1.x * xv.y + w2.x * xv.z + w3.x * xv.w;
        ay += w0.y * xv.x + w1.y * xv.y + w2.y * xv.z + w3.y * xv.w;
        az += w0.z * xv.x + w1.z * xv.y + w2.z * xv.z + w3.z * xv.w;
        aw += w0.w * xv.x + w1.w * xv.y + w2.w * xv.z + w3.w * xv.w;
      }
      *(float4*)&partial[g][4 * c] = make_float4(ax, ay, az, aw);
      __syncthreads();  // also guarantees every thread's xs reads are done
      if (tid < NN) {
        float arg = rInp;
        #pragma unroll
        for (int gg = 0; gg < 8; ++gg) arg += partial[gg][tid];
        float f  = tanhf(arg);
        float xo = xs[tid];
        float xn = fmaf(dtk * f, rA, xo) / fmaf(dtk, rInvTau + f, 1.0f);
        xcur = xn;
        xs[tid] = xn;   // safe: all GEMV reads of xs precede the barrier above
      }
      __syncthreads();
    }
    if (tid < NN) outb[(size_t)t * NN + tid] = xcur;
  }
}

extern "C" void kernel_launch(void* const* d_in, const int* in_sizes, int n_in,
                              void* d_out, int out_size, void* d_ws, size_t ws_size,
                              hipStream_t stream) {
  const float* I    = (const float*)d_in[0];
  const float* DT   = (const float*)d_in[1];
  const float* Wrec = (const float*)d_in[2];  // [N][N]
  const float* Win  = (const float*)d_in[3];  // [N][F]
  const float* bv   = (const float*)d_in[4];
  const float* Av   = (const float*)d_in[5];
  const float* tauv = (const float*)d_in[6];
  float* out = (float*)d_out;

  float* WrT = (float*)d_ws;            // 512*512 floats = 1 MB
  float* WiT = WrT + NN * NN;           // 256*512 floats = 512 KB

  dim3 tb(32, 8);
  transpose_k<<<dim3(NN / 32, NN / 32), tb, 0, stream>>>(Wrec, WrT, NN, NN);
  transpose_k<<<dim3(FF / 32, NN / 32), tb, 0, stream>>>(Win,  WiT, NN, FF);
  liquid_kernel<<<BB, 1024, 0, stream>>>(I, DT, WrT, WiT, bv, Av, tauv, out);
}